// Round 1
// baseline (603.984 us; speedup 1.0000x reference)
//
#include <hip/hip_runtime.h>

// GwcVolume: group-wise correlation cost volume. FP32 in / FP32 out.
// B=1, F=320, G=40 groups, C=8 ch/group, H=128, W=256, D=48 disparities.
// lr[g,d,h,w] = (w>=d) ? mean_c L[g,c,h,w]*R[g,c,h,w-d] : 0
// rl[g,d,h,w] = lr row rotated left by d (masked head lands on rl's zero tail).
//
// Round-1 restructure (write-stream locality theory):
// old: wave owns (g,h), loops d -> 1KB write islands at 128KB stride (96/wave),
//      measured ~2.3 TB/s effective (~2.7x off the 6.3 TB/s roofline).
// new: block (4 waves) owns (g, 16-d-slab, 8-h-strip); wave keeps ONE 4-d batch
//      and streams h. Each wave's 8 output streams (4d x 2vol) advance
//      sequentially 1KB/iter over 8KB -> DRAM row locality like the fill.
// Compute tricks preserved: L quads in regs, R windows amortized over 4 d,
// rl = pure rotation (no extra FMA/LDS). R row staged once per block per h
// via global_load_lds (8KB, shared by all 4 waves); L row re-read per wave
// but L1-resident (identical row across the block's waves).

#define G_     40
#define CPG    8
#define H_     128
#define W_     256
#define HW_    (H_ * W_)
#define HSTRIP 8

typedef __attribute__((address_space(1))) const unsigned int gu32;
typedef __attribute__((address_space(3))) unsigned int lu32;

__device__ __forceinline__ void gload16(const float* gp, float* lp) {
    // 16B/lane async global->LDS; LDS dest = uniform base + lane*16 (linear).
    __builtin_amdgcn_global_load_lds((gu32*)gp, (lu32*)lp, 16, 0, 0);
}

__global__ __launch_bounds__(256, 4)
void gwc_volume_kernel(const float* __restrict__ Lp,
                       const float* __restrict__ Rp,
                       const int* __restrict__ bins,
                       float* __restrict__ out,
                       int D)
{
    __shared__ float Rrow[CPG * W_];   // 8 KB: current (g,h) right row, all ch
    __shared__ int   bins_s[64];

    const int tid = threadIdx.x;
    const int wv  = tid >> 6;          // wave 0..3
    const int ln  = tid & 63;
    const int w4  = ln << 2;           // this lane's 4 w positions

    if (tid < D) bins_s[tid] = bins[tid];

    // block -> (g, db, h-strip), XCD-contiguous bijective remap (1920 % 8 == 0)
    const int nH  = H_ / HSTRIP;       // 16
    const int nD  = D >> 4;            // 3 (16 disparities per block)
    int bx = blockIdx.x;
    const int cpx = (G_ * nD * nH) >> 3;          // 240 blocks per XCD
    bx = (bx & 7) * cpx + (bx >> 3);

    const int g  = bx / (nD * nH);
    const int r0 = bx - g * (nD * nH);
    const int db = r0 / nH;
    const int h0 = (r0 - db * nH) * HSTRIP;

    const int di0 = db * 16 + wv * 4;  // this wave's disparity-index batch

    __syncthreads();                   // bins_s visible
    const int d0   = bins_s[di0];
    const int base = w4 - d0;
    const int ihi  = (base     < 0) ? 0 : base;      // loop-invariant windows
    const int ilo  = (base - 4 < 0) ? 0 : base - 4;  // (clamped lanes masked)

    const size_t grow = (size_t)(g * CPG) * HW_ + (size_t)h0 * W_;
    float* out_rl = out + (size_t)G_ * D * HW_;
    const int c0 = wv * 2;             // this wave stages channels c0, c0+1

    #pragma unroll 1
    for (int hh = 0; hh < HSTRIP; ++hh) {
        const size_t in_row = grow + (size_t)hh * W_;

        if (hh) __syncthreads();       // prior readers of Rrow are done
        gload16(Rp + in_row + (size_t)c0       * HW_ + ln * 4, &Rrow[c0 * W_]);
        gload16(Rp + in_row + (size_t)(c0 + 1) * HW_ + ln * 4, &Rrow[(c0 + 1) * W_]);

        // Left quads -> regs (pre-scaled by 1/C); identical row for all 4
        // waves of this block -> L1-served after the first.
        float4 lf[CPG];
        #pragma unroll
        for (int c = 0; c < CPG; ++c) {
            float4 lv = *(const float4*)(Lp + in_row + (size_t)c * HW_ + w4);
            lf[c] = make_float4(lv.x * 0.125f, lv.y * 0.125f,
                                lv.z * 0.125f, lv.w * 0.125f);
        }

        __syncthreads();               // Rrow staged (compiler drains vmcnt)

        float4 a0 = make_float4(0.f, 0.f, 0.f, 0.f);
        float4 a1 = a0, a2 = a0, a3 = a0;
        #pragma unroll
        for (int c = 0; c < CPG; ++c) {
            const float* rr  = &Rrow[c * W_];
            float4 rlo = *(const float4*)(rr + ilo);
            float4 rhi = *(const float4*)(rr + ihi);
            float4 lc  = lf[c];
            // d = d0+0 : R indices w4+j-d0 -> rhi.xyzw
            a0.x = fmaf(lc.x, rhi.x, a0.x); a0.y = fmaf(lc.y, rhi.y, a0.y);
            a0.z = fmaf(lc.z, rhi.z, a0.z); a0.w = fmaf(lc.w, rhi.w, a0.w);
            // d = d0+1
            a1.x = fmaf(lc.x, rlo.w, a1.x); a1.y = fmaf(lc.y, rhi.x, a1.y);
            a1.z = fmaf(lc.z, rhi.y, a1.z); a1.w = fmaf(lc.w, rhi.z, a1.w);
            // d = d0+2
            a2.x = fmaf(lc.x, rlo.z, a2.x); a2.y = fmaf(lc.y, rlo.w, a2.y);
            a2.z = fmaf(lc.z, rhi.x, a2.z); a2.w = fmaf(lc.w, rhi.y, a2.w);
            // d = d0+3
            a3.x = fmaf(lc.x, rlo.y, a3.x); a3.y = fmaf(lc.y, rlo.z, a3.y);
            a3.z = fmaf(lc.z, rlo.w, a3.z); a3.w = fmaf(lc.w, rhi.x, a3.w);
        }

        const size_t orow = (size_t)(g * D + di0) * HW_
                          + (size_t)(h0 + hh) * W_;
        float4 av[4] = {a0, a1, a2, a3};
        #pragma unroll
        for (int dd = 0; dd < 4; ++dd) {
            const int d = d0 + dd;
            float4 a = av[dd];
            float4 v;
            v.x = (w4 + 0 >= d) ? a.x : 0.f;
            v.y = (w4 + 1 >= d) ? a.y : 0.f;
            v.z = (w4 + 2 >= d) ? a.z : 0.f;
            v.w = (w4 + 3 >= d) ? a.w : 0.f;

            const size_t o = orow + (size_t)dd * HW_;
            *(float4*)(out + o + w4) = v;            // lr: aligned 16B

            // rl row = lr row rotated left by d (masked head -> zero tail).
            float* ro = out_rl + o;
            ro[(w4 + 0 - d) & (W_ - 1)] = v.x;
            ro[(w4 + 1 - d) & (W_ - 1)] = v.y;
            ro[(w4 + 2 - d) & (W_ - 1)] = v.z;
            ro[(w4 + 3 - d) & (W_ - 1)] = v.w;
        }
    }
}

extern "C" void kernel_launch(void* const* d_in, const int* in_sizes, int n_in,
                              void* d_out, int out_size, void* d_ws, size_t ws_size,
                              hipStream_t stream) {
    const float* L  = (const float*)d_in[0];
    const float* R  = (const float*)d_in[1];
    const int* bins = (const int*)d_in[2];
    float* out      = (float*)d_out;
    const int D = in_sizes[2];                        // 48
    const int blocks = G_ * (H_ / HSTRIP) * (D >> 4); // 40*16*3 = 1920
    gwc_volume_kernel<<<blocks, 256, 0, stream>>>(L, R, bins, out, D);
}